// Round 13
// baseline (232.853 us; speedup 1.0000x reference)
//
#include <hip/hip_runtime.h>
#include <cstddef>

#define N_NODES 100000
#define N_EDGES 1600000
#define NCHUNK32 3125   // N_NODES / 32, exact
#define GEMM_BLOCKS ((NCHUNK32 + 3) / 4)      // 782
#define BUCK_SHIFT 6
#define BUCK_NODES 64                         // nodes per bucket (pow2: no div)
#define NBUCK 1563                            // ceil(N_NODES / 64)
#define EB_CAP 1536     // mean 1024, sigma ~32 -> +16 sigma
#define BF_EDGES 8192
#define BF_BLOCKS ((N_EDGES + BF_EDGES - 1) / BF_EDGES)   // 196

typedef __attribute__((ext_vector_type(8))) short short8;   // 8 bf16 = 4 VGPRs
typedef __attribute__((ext_vector_type(4))) float f32x4;
typedef __attribute__((ext_vector_type(2))) float f32x2;

__device__ __forceinline__ unsigned pack_bf16x2(float a, float b) {
  unsigned ua = __float_as_uint(a); ua += 0x7FFFu + ((ua >> 16) & 1u);
  unsigned ub = __float_as_uint(b); ub += 0x7FFFu + ((ub >> 16) & 1u);
  return (ua >> 16) | (ub & 0xFFFF0000u);
}

// ====== init: cursors + gsum + done flag + fragment-ordered W2 buffer ======
__global__ __launch_bounds__(512) void k_init(int* __restrict__ bucket_cursor,
                                              float* __restrict__ gsum,
                                              int* __restrict__ done,
                                              const float* __restrict__ W2_rel,
                                              const float* __restrict__ W2_root,
                                              unsigned* __restrict__ wbuf) {
  int t = threadIdx.x;
  for (int b = t; b < NBUCK; b += 512) bucket_cursor[b] = b * EB_CAP;
  if (t < 128) gsum[t] = 0.0f;
  if (t == 0) *done = 0;
#pragma unroll
  for (int i = 0; i < 8; ++i) {
    int e = t + i * 512;                    // 0..4095
    int L = e & 63, T = (e >> 6) & 7, K0 = e >> 9;
    int f = T * 16 + (L & 15);
    int k0 = K0 * 32 + ((L >> 4) << 3);     // 8-aligned; never crosses 128
    const float* wsrc = (k0 < 128) ? (W2_rel + f * 128 + k0)
                                   : (W2_root + f * 128 + (k0 - 128));
    float4 w0 = *(const float4*)(wsrc);
    float4 w1 = *(const float4*)(wsrc + 4);
    unsigned* d = wbuf + e * 4;
    d[0] = pack_bf16x2(w0.x, w0.y);
    d[1] = pack_bf16x2(w0.z, w0.w);
    d[2] = pack_bf16x2(w1.x, w1.y);
    d[3] = pack_bf16x2(w1.z, w1.w);
  }
}

// ============ CSR build pass 1: bucket-scatter packed edges ============
// packed edge = (dst_local << 17) | src
__global__ __launch_bounds__(512) void k_bfill(const int* __restrict__ src,
                                               const int* __restrict__ dst,
                                               int* __restrict__ bucket_cursor,
                                               unsigned* __restrict__ ebuf) {
  __shared__ int lh[NBUCK];
  __shared__ int sub_base[NBUCK];
  __shared__ int cur[NBUCK];
  int t = threadIdx.x;
  for (int b = t; b < NBUCK; b += 512) { lh[b] = 0; cur[b] = 0; }
  __syncthreads();
  int e0 = blockIdx.x * BF_EDGES;
  unsigned pk[16];
  int bk[16];
#pragma unroll
  for (int i = 0; i < 16; ++i) {
    int e = e0 + i * 512 + t;
    bk[i] = -1;
    if (e < N_EDGES) {
      int d = dst[e];
      int b = d >> BUCK_SHIFT;
      bk[i] = b;
      pk[i] = ((unsigned)(d & (BUCK_NODES - 1)) << 17) | (unsigned)src[e];
      atomicAdd(&lh[b], 1);
    }
  }
  __syncthreads();
  for (int b = t; b < NBUCK; b += 512)
    sub_base[b] = (lh[b] > 0) ? atomicAdd(&bucket_cursor[b], lh[b]) : 0;
  __syncthreads();
#pragma unroll
  for (int i = 0; i < 16; ++i) {
    if (bk[i] >= 0) {
      int pos = sub_base[bk[i]] + atomicAdd(&cur[bk[i]], 1);
      if (pos < (bk[i] + 1) * EB_CAP) ebuf[pos] = pk[i];  // +16 sigma guard
    }
  }
}

// ====== CSR build pass 2 + layer-1 (fused): one block per 64-node bucket ====
__global__ __launch_bounds__(256) void k_fill2(
    const unsigned* __restrict__ ebuf, const int* __restrict__ bucket_cursor,
    const float* __restrict__ x, const float* __restrict__ W1_rel,
    const float* __restrict__ b1, const float* __restrict__ W1_root,
    int* __restrict__ row_start, int* __restrict__ row_end,
    int* __restrict__ csr_src, unsigned short* __restrict__ h1f8) {
  __shared__ int cnt[BUCK_NODES];
  __shared__ int start[BUCK_NODES];
  __shared__ float sagg[BUCK_NODES * 4];
  __shared__ float sx[BUCK_NODES * 4];
  __shared__ float sWa[8 * 128];
  __shared__ float sb1[128];
  int t = threadIdx.x;
  int b = blockIdx.x;
  int base = b * EB_CAP;
  int nb = bucket_cursor[b] - base;
  if (nb > EB_CAP) nb = EB_CAP;
  int n0 = b << BUCK_SHIFT;

  if (t < 128) {
    float4 wr = *(const float4*)(W1_rel + t * 4);
    float4 wo = *(const float4*)(W1_root + t * 4);
    sWa[0 * 128 + t] = wr.x; sWa[1 * 128 + t] = wr.y;
    sWa[2 * 128 + t] = wr.z; sWa[3 * 128 + t] = wr.w;
    sWa[4 * 128 + t] = wo.x; sWa[5 * 128 + t] = wo.y;
    sWa[6 * 128 + t] = wo.z; sWa[7 * 128 + t] = wo.w;
    sb1[t] = b1[t];
  }
  if (t < BUCK_NODES) {
    cnt[t] = 0;
    float4 xv = make_float4(0.f, 0.f, 0.f, 0.f);
    if (n0 + t < N_NODES) xv = *(const float4*)(x + (size_t)(n0 + t) * 4);
    *(float4*)&sx[t * 4] = xv;
  }
  __syncthreads();

  for (int i = t; i < nb; i += 256) atomicAdd(&cnt[ebuf[base + i] >> 17], 1);
  __syncthreads();
  if (t < 64) {
    int v = cnt[t];
    int incl = v;
#pragma unroll
    for (int off = 1; off < 64; off <<= 1) {
      int nvv = __shfl_up(incl, off);
      if (t >= off) incl += nvv;
    }
    int excl = incl - v;
    start[t] = excl;
    cnt[t] = excl;          // becomes fill cursor
    if (n0 + t < N_NODES) row_start[n0 + t] = base + excl;
  }
  __syncthreads();
  for (int i = t; i < nb; i += 256) {
    unsigned e = ebuf[base + i];
    int p = atomicAdd(&cnt[e >> 17], 1);
    csr_src[base + p] = (int)(e & 0x1FFFFu);
  }
  __syncthreads();
  {
    int nd = t >> 2, sub = t & 3;
    int rs = base + start[nd];
    int re = base + cnt[nd];
    float4 acc = make_float4(0.f, 0.f, 0.f, 0.f);
    for (int i = rs + sub; i < re; i += 4) {
      int s = csr_src[i];
      float4 v = *(const float4*)(x + (size_t)s * 4);
      acc.x += v.x; acc.y += v.y; acc.z += v.z; acc.w += v.w;
    }
#pragma unroll
    for (int off = 1; off < 4; off <<= 1) {
      acc.x += __shfl_xor(acc.x, off);
      acc.y += __shfl_xor(acc.y, off);
      acc.z += __shfl_xor(acc.z, off);
      acc.w += __shfl_xor(acc.w, off);
    }
    if (sub == 0) *(float4*)&sagg[nd * 4] = acc;
    if (t < 64 && n0 + t < N_NODES) row_end[n0 + t] = base + cnt[t];
  }
  __syncthreads();

  for (int it = t; it < BUCK_NODES * 64; it += 256) {
    int nd = it >> 6;
    if (n0 + nd >= N_NODES) break;
    int fp = it & 63;
    int f = fp * 2;
    float4 a  = *(float4*)&sagg[nd * 4];
    float4 xv = *(float4*)&sx[nd * 4];
    float v0 = sb1[f]
        + a.x  * sWa[0 * 128 + f] + a.y  * sWa[1 * 128 + f]
        + a.z  * sWa[2 * 128 + f] + a.w  * sWa[3 * 128 + f]
        + xv.x * sWa[4 * 128 + f] + xv.y * sWa[5 * 128 + f]
        + xv.z * sWa[6 * 128 + f] + xv.w * sWa[7 * 128 + f];
    int f1 = f + 1;
    float v1 = sb1[f1]
        + a.x  * sWa[0 * 128 + f1] + a.y  * sWa[1 * 128 + f1]
        + a.z  * sWa[2 * 128 + f1] + a.w  * sWa[3 * 128 + f1]
        + xv.x * sWa[4 * 128 + f1] + xv.y * sWa[5 * 128 + f1]
        + xv.z * sWa[6 * 128 + f1] + xv.w * sWa[7 * 128 + f1];
    float r0 = fmaxf(v0, 0.f), r1 = fmaxf(v1, 0.f);
    h1f8[(size_t)(n0 + nd) * 64 + fp] =
        (unsigned short)__builtin_amdgcn_cvt_pk_fp8_f32(r0, r1, 0, false);
  }
}

// ============ layer 2 aggregate: split-wave paired FP8 gather ============
// One wave per dst node; lanes 0-31 gather edge j, lanes 32-63 edge j+1
// (each lane loads a uint = 4 fp8 features). Per 2 edges: 1 load + 1 shfl
// (was 2+2). Halves combined via shfl_xor(32); 256B coalesced uint2 write.
__global__ __launch_bounds__(256) void k_pull128(
    const unsigned* __restrict__ h1f8_u, const int* __restrict__ row_start,
    const int* __restrict__ row_end, const int* __restrict__ csr_src,
    uint2* __restrict__ agg2b) {
  int w = (blockIdx.x * 256 + threadIdx.x) >> 6;
  if (w >= N_NODES) return;
  int lane = threadIdx.x & 63;
  int half = lane >> 5;     // which edge of the pair
  int hl = lane & 31;       // feature-quad index: features 4*hl..4*hl+3
  int rs = row_start[w], re = row_end[w];
  float a0 = 0.f, a1 = 0.f, a2 = 0.f, a3 = 0.f;
  for (int chunk = rs; chunk < re; chunk += 64) {
    int nv = min(64, re - chunk);
    int sv = (chunk + lane < re) ? csr_src[chunk + lane] : 0;
    int j = 0;
    for (; j + 8 <= nv; j += 8) {       // 4 pair-loads in flight (8 edges)
      int s0 = __shfl(sv, j + 0 + half);
      int s1 = __shfl(sv, j + 2 + half);
      int s2 = __shfl(sv, j + 4 + half);
      int s3 = __shfl(sv, j + 6 + half);
      unsigned u0 = h1f8_u[(size_t)s0 * 32 + hl];
      unsigned u1 = h1f8_u[(size_t)s1 * 32 + hl];
      unsigned u2 = h1f8_u[(size_t)s2 * 32 + hl];
      unsigned u3 = h1f8_u[(size_t)s3 * 32 + hl];
      f32x2 l0 = __builtin_amdgcn_cvt_pk_f32_fp8((int)u0, false);
      f32x2 h0 = __builtin_amdgcn_cvt_pk_f32_fp8((int)u0, true);
      f32x2 l1 = __builtin_amdgcn_cvt_pk_f32_fp8((int)u1, false);
      f32x2 h1 = __builtin_amdgcn_cvt_pk_f32_fp8((int)u1, true);
      f32x2 l2 = __builtin_amdgcn_cvt_pk_f32_fp8((int)u2, false);
      f32x2 h2 = __builtin_amdgcn_cvt_pk_f32_fp8((int)u2, true);
      f32x2 l3 = __builtin_amdgcn_cvt_pk_f32_fp8((int)u3, false);
      f32x2 h3 = __builtin_amdgcn_cvt_pk_f32_fp8((int)u3, true);
      a0 += l0.x + l1.x + l2.x + l3.x;
      a1 += l0.y + l1.y + l2.y + l3.y;
      a2 += h0.x + h1.x + h2.x + h3.x;
      a3 += h0.y + h1.y + h2.y + h3.y;
    }
    for (; j + 2 <= nv; j += 2) {       // paired tail
      int s0 = __shfl(sv, j + half);
      unsigned u0 = h1f8_u[(size_t)s0 * 32 + hl];
      f32x2 l0 = __builtin_amdgcn_cvt_pk_f32_fp8((int)u0, false);
      f32x2 h0 = __builtin_amdgcn_cvt_pk_f32_fp8((int)u0, true);
      a0 += l0.x; a1 += l0.y; a2 += h0.x; a3 += h0.y;
    }
    if (j < nv) {                        // odd single: half 0 only
      int s0 = __shfl(sv, j);
      unsigned u0 = h1f8_u[(size_t)s0 * 32 + hl];
      if (half == 0) {
        f32x2 l0 = __builtin_amdgcn_cvt_pk_f32_fp8((int)u0, false);
        f32x2 h0 = __builtin_amdgcn_cvt_pk_f32_fp8((int)u0, true);
        a0 += l0.x; a1 += l0.y; a2 += h0.x; a3 += h0.y;
      }
    }
  }
  a0 += __shfl_xor(a0, 32);
  a1 += __shfl_xor(a1, 32);
  a2 += __shfl_xor(a2, 32);
  a3 += __shfl_xor(a3, 32);
  if (half == 0) {
    uint2 o;
    o.x = pack_bf16x2(a0, a1);
    o.y = pack_bf16x2(a2, a3);
    agg2b[(size_t)w * 32 + hl] = o;
  }
}

// ====== layer 2 dense + pool + FUSED head: MFMA GEMM, 32-node waves ======
__global__ __launch_bounds__(256) void k_gemm_pool(
    const unsigned* __restrict__ agg2b_u, const unsigned short* __restrict__ h1f8,
    const unsigned* __restrict__ wbuf_u, const float* __restrict__ b2,
    float* __restrict__ gsum, int* __restrict__ done,
    const float* __restrict__ Wlin, const float* __restrict__ blin,
    float* __restrict__ out) {
  __shared__ float lgs[128];
  __shared__ int amlast;
  int t = threadIdx.x;
  if (t < 128) lgs[t] = 0.0f;
  __syncthreads();

  int lane = t & 63;
  int gw = blockIdx.x * 4 + (t >> 6);
  int lrow = lane & 15;
  int quad = lane >> 4;
  const unsigned short* agg2b = (const unsigned short*)agg2b_u;
  const unsigned char* h8 = (const unsigned char*)h1f8;
  const short8* wb = (const short8*)wbuf_u;

  float bias[8];
#pragma unroll
  for (int tt = 0; tt < 8; ++tt) bias[tt] = b2[tt * 16 + lrow];
  float csum[8] = {0.f, 0.f, 0.f, 0.f, 0.f, 0.f, 0.f, 0.f};

  if (gw < NCHUNK32) {
    int mbase = gw * 32;

    f32x4 acc[2][8];
#pragma unroll
    for (int mt = 0; mt < 2; ++mt)
#pragma unroll
      for (int tt = 0; tt < 8; ++tt) acc[mt][tt] = (f32x4){0.f, 0.f, 0.f, 0.f};

#pragma unroll
    for (int ks = 0; ks < 4; ++ks) {
      const unsigned short* abase = agg2b + ks * 32 + quad * 8;
      short8 afr[2];
#pragma unroll
      for (int mt = 0; mt < 2; ++mt)
        afr[mt] = *(const short8*)(abase + (size_t)(mbase + mt * 16 + lrow) * 128);
      short8 bfr[8];
#pragma unroll
      for (int tt = 0; tt < 8; ++tt) bfr[tt] = wb[(ks * 8 + tt) * 64 + lane];
#pragma unroll
      for (int mt = 0; mt < 2; ++mt)
#pragma unroll
        for (int tt = 0; tt < 8; ++tt)
          acc[mt][tt] = __builtin_amdgcn_mfma_f32_16x16x32_bf16(
              afr[mt], bfr[tt], acc[mt][tt], 0, 0, 0);
    }
#pragma unroll
    for (int ks = 4; ks < 8; ++ks) {
      short8 afr[2];
#pragma unroll
      for (int mt = 0; mt < 2; ++mt) {
        const uint2* ap = (const uint2*)(h8 + (size_t)(mbase + mt * 16 + lrow) * 128
                                         + (ks - 4) * 32 + quad * 8);
        uint2 u = *ap;
        f32x2 a0 = __builtin_amdgcn_cvt_pk_f32_fp8((int)u.x, false);
        f32x2 a1 = __builtin_amdgcn_cvt_pk_f32_fp8((int)u.x, true);
        f32x2 a2 = __builtin_amdgcn_cvt_pk_f32_fp8((int)u.y, false);
        f32x2 a3 = __builtin_amdgcn_cvt_pk_f32_fp8((int)u.y, true);
        unsigned q[4] = {pack_bf16x2(a0.x, a0.y), pack_bf16x2(a1.x, a1.y),
                         pack_bf16x2(a2.x, a2.y), pack_bf16x2(a3.x, a3.y)};
        afr[mt] = *(short8*)q;
      }
      short8 bfr[8];
#pragma unroll
      for (int tt = 0; tt < 8; ++tt) bfr[tt] = wb[(ks * 8 + tt) * 64 + lane];
#pragma unroll
      for (int mt = 0; mt < 2; ++mt)
#pragma unroll
        for (int tt = 0; tt < 8; ++tt)
          acc[mt][tt] = __builtin_amdgcn_mfma_f32_16x16x32_bf16(
              afr[mt], bfr[tt], acc[mt][tt], 0, 0, 0);
    }

#pragma unroll
    for (int mt = 0; mt < 2; ++mt) {
#pragma unroll
      for (int tt = 0; tt < 8; ++tt) {
        f32x4 v = acc[mt][tt];
        float s = fmaxf(v.x + bias[tt], 0.f) + fmaxf(v.y + bias[tt], 0.f)
                + fmaxf(v.z + bias[tt], 0.f) + fmaxf(v.w + bias[tt], 0.f);
        s += __shfl_xor(s, 16);
        s += __shfl_xor(s, 32);
        csum[tt] += s;
      }
    }
  }
  if (lane < 16) {
#pragma unroll
    for (int tt = 0; tt < 8; ++tt) atomicAdd(&lgs[tt * 16 + lane], csum[tt]);
  }
  __syncthreads();
  if (t < 128) atomicAdd(&gsum[t], lgs[t]);

  // ---- fused head: last block computes out = (gsum/N)@Wlin.T + blin ----
  __threadfence();
  if (t == 0) amlast = (atomicAdd(done, 1) == (int)gridDim.x - 1);
  __syncthreads();
  if (amlast && t < 64) {
    // atomic fetch-add(0) reads bypass stale L1 and see all blocks' atomics
    float g0 = atomicAdd(&gsum[t], 0.0f);
    float g1 = atomicAdd(&gsum[t + 64], 0.0f);
    float s0 = g0 * Wlin[t]       + g1 * Wlin[t + 64];
    float s1 = g0 * Wlin[128 + t] + g1 * Wlin[192 + t];
#pragma unroll
    for (int off = 32; off > 0; off >>= 1) {
      s0 += __shfl_down(s0, off);
      s1 += __shfl_down(s1, off);
    }
    if (t == 0) {
      const float inv = 1.0f / (float)N_NODES;
      out[0] = s0 * inv + blin[0];
      out[1] = s1 * inv + blin[1];
    }
  }
}

extern "C" void kernel_launch(void* const* d_in, const int* in_sizes, int n_in,
                              void* d_out, int out_size, void* d_ws, size_t ws_size,
                              hipStream_t stream) {
  const float* x       = (const float*)d_in[0];
  const int*   ei      = (const int*)d_in[1];
  const float* W1_rel  = (const float*)d_in[2];
  const float* b1      = (const float*)d_in[3];
  const float* W1_root = (const float*)d_in[4];
  const float* W2_rel  = (const float*)d_in[5];
  const float* b2      = (const float*)d_in[6];
  const float* W2_root = (const float*)d_in[7];
  const float* Wlin    = (const float*)d_in[8];
  const float* blin    = (const float*)d_in[9];
  const int* src = ei;            // edge_index[0]
  const int* dst = ei + N_EDGES;  // edge_index[1]
  float* out = (float*)d_out;

  // workspace layout (bytes):
  //   row_start     @0          : 400,000
  //   row_end       @400,000    : 400,000
  //   bucket_cursor @800,000    : 8,192
  //   gsum          @808,192    : 512
  //   done          @808,704    : 128
  //   wbuf          @808,832    : 65,536     -> 874,368
  //   csr_src       @874,368    : 9,603,072  -> 10,477,440
  //   ebuf (uint)   @10,477,440 : 9,603,072  -> 20,080,512
  //   h1f8 (fp8)    @20,080,512 : 12,800,000 -> 32,880,512
  //   agg2b (bf16)  @32,880,512 : 25,600,000 -> 58,480,512
  char* ws = (char*)d_ws;
  int*            row_start     = (int*)(ws);
  int*            row_end       = (int*)(ws + 400000);
  int*            bucket_cursor = (int*)(ws + 800000);
  float*          gsum          = (float*)(ws + 808192);
  int*            done          = (int*)(ws + 808704);
  unsigned*       wbuf          = (unsigned*)(ws + 808832);
  int*            csr_src       = (int*)(ws + 874368);
  unsigned*       ebuf          = (unsigned*)(ws + 10477440);
  unsigned short* h1f8          = (unsigned short*)(ws + 20080512);
  uint2*          agg2b         = (uint2*)(ws + 32880512);

  k_init <<<1, 512, 0, stream>>>(bucket_cursor, gsum, done, W2_rel, W2_root, wbuf);
  k_bfill<<<BF_BLOCKS, 512, 0, stream>>>(src, dst, bucket_cursor, ebuf);
  k_fill2<<<NBUCK, 256, 0, stream>>>(ebuf, bucket_cursor, x, W1_rel, b1, W1_root,
                                     row_start, row_end, csr_src, h1f8);
  k_pull128<<<(N_NODES * 64 + 255) / 256, 256, 0, stream>>>(
      (const unsigned*)h1f8, row_start, row_end, csr_src, agg2b);
  k_gemm_pool<<<GEMM_BLOCKS, 256, 0, stream>>>(
      (const unsigned*)agg2b, h1f8, wbuf, b2, gsum, done, Wlin, blin, out);
}

// Round 14
// 204.273 us; speedup vs baseline: 1.1399x; 1.1399x over previous
//
#include <hip/hip_runtime.h>
#include <cstddef>

#define N_NODES 100000
#define N_EDGES 1600000
#define NCHUNK32 3125   // N_NODES / 32, exact
#define GEMM_BLOCKS ((NCHUNK32 + 3) / 4)      // 782
#define BUCK_SHIFT 6
#define BUCK_NODES 64                         // nodes per bucket (pow2: no div)
#define NBUCK 1563                            // ceil(N_NODES / 64)
#define EB_CAP 1536     // mean 1024, sigma ~32 -> +16 sigma
#define BF_EDGES 8192
#define BF_BLOCKS ((N_EDGES + BF_EDGES - 1) / BF_EDGES)   // 196

typedef __attribute__((ext_vector_type(8))) short short8;   // 8 bf16 = 4 VGPRs
typedef __attribute__((ext_vector_type(4))) float f32x4;
typedef __attribute__((ext_vector_type(2))) float f32x2;

__device__ __forceinline__ unsigned pack_bf16x2(float a, float b) {
  unsigned ua = __float_as_uint(a); ua += 0x7FFFu + ((ua >> 16) & 1u);
  unsigned ub = __float_as_uint(b); ub += 0x7FFFu + ((ub >> 16) & 1u);
  return (ua >> 16) | (ub & 0xFFFF0000u);
}

// ====== init: cursors + gsum + fragment-ordered W2 buffer ======
__global__ __launch_bounds__(512) void k_init(int* __restrict__ bucket_cursor,
                                              float* __restrict__ gsum,
                                              const float* __restrict__ W2_rel,
                                              const float* __restrict__ W2_root,
                                              unsigned* __restrict__ wbuf) {
  int t = threadIdx.x;
  for (int b = t; b < NBUCK; b += 512) bucket_cursor[b] = b * EB_CAP;
  if (t < 128) gsum[t] = 0.0f;
#pragma unroll
  for (int i = 0; i < 8; ++i) {
    int e = t + i * 512;                    // 0..4095
    int L = e & 63, T = (e >> 6) & 7, K0 = e >> 9;
    int f = T * 16 + (L & 15);
    int k0 = K0 * 32 + ((L >> 4) << 3);     // 8-aligned; never crosses 128
    const float* wsrc = (k0 < 128) ? (W2_rel + f * 128 + k0)
                                   : (W2_root + f * 128 + (k0 - 128));
    float4 w0 = *(const float4*)(wsrc);
    float4 w1 = *(const float4*)(wsrc + 4);
    unsigned* d = wbuf + e * 4;
    d[0] = pack_bf16x2(w0.x, w0.y);
    d[1] = pack_bf16x2(w0.z, w0.w);
    d[2] = pack_bf16x2(w1.x, w1.y);
    d[3] = pack_bf16x2(w1.z, w1.w);
  }
}

// ============ CSR build pass 1: bucket-scatter packed edges ============
// packed edge = (dst_local << 17) | src
__global__ __launch_bounds__(512) void k_bfill(const int* __restrict__ src,
                                               const int* __restrict__ dst,
                                               int* __restrict__ bucket_cursor,
                                               unsigned* __restrict__ ebuf) {
  __shared__ int lh[NBUCK];
  __shared__ int sub_base[NBUCK];
  __shared__ int cur[NBUCK];
  int t = threadIdx.x;
  for (int b = t; b < NBUCK; b += 512) { lh[b] = 0; cur[b] = 0; }
  __syncthreads();
  int e0 = blockIdx.x * BF_EDGES;
  unsigned pk[16];
  int bk[16];
#pragma unroll
  for (int i = 0; i < 16; ++i) {
    int e = e0 + i * 512 + t;
    bk[i] = -1;
    if (e < N_EDGES) {
      int d = dst[e];
      int b = d >> BUCK_SHIFT;
      bk[i] = b;
      pk[i] = ((unsigned)(d & (BUCK_NODES - 1)) << 17) | (unsigned)src[e];
      atomicAdd(&lh[b], 1);
    }
  }
  __syncthreads();
  for (int b = t; b < NBUCK; b += 512)
    sub_base[b] = (lh[b] > 0) ? atomicAdd(&bucket_cursor[b], lh[b]) : 0;
  __syncthreads();
#pragma unroll
  for (int i = 0; i < 16; ++i) {
    if (bk[i] >= 0) {
      int pos = sub_base[bk[i]] + atomicAdd(&cur[bk[i]], 1);
      if (pos < (bk[i] + 1) * EB_CAP) ebuf[pos] = pk[i];  // +16 sigma guard
    }
  }
}

// ====== CSR build pass 2 + layer-1 (fused): one block per 64-node bucket ====
__global__ __launch_bounds__(256) void k_fill2(
    const unsigned* __restrict__ ebuf, const int* __restrict__ bucket_cursor,
    const float* __restrict__ x, const float* __restrict__ W1_rel,
    const float* __restrict__ b1, const float* __restrict__ W1_root,
    int* __restrict__ row_start, int* __restrict__ row_end,
    int* __restrict__ csr_src, unsigned short* __restrict__ h1f8) {
  __shared__ int cnt[BUCK_NODES];
  __shared__ int start[BUCK_NODES];
  __shared__ float sagg[BUCK_NODES * 4];
  __shared__ float sx[BUCK_NODES * 4];
  __shared__ float sWa[8 * 128];
  __shared__ float sb1[128];
  int t = threadIdx.x;
  int b = blockIdx.x;
  int base = b * EB_CAP;
  int nb = bucket_cursor[b] - base;
  if (nb > EB_CAP) nb = EB_CAP;
  int n0 = b << BUCK_SHIFT;

  if (t < 128) {
    float4 wr = *(const float4*)(W1_rel + t * 4);
    float4 wo = *(const float4*)(W1_root + t * 4);
    sWa[0 * 128 + t] = wr.x; sWa[1 * 128 + t] = wr.y;
    sWa[2 * 128 + t] = wr.z; sWa[3 * 128 + t] = wr.w;
    sWa[4 * 128 + t] = wo.x; sWa[5 * 128 + t] = wo.y;
    sWa[6 * 128 + t] = wo.z; sWa[7 * 128 + t] = wo.w;
    sb1[t] = b1[t];
  }
  if (t < BUCK_NODES) {
    cnt[t] = 0;
    float4 xv = make_float4(0.f, 0.f, 0.f, 0.f);
    if (n0 + t < N_NODES) xv = *(const float4*)(x + (size_t)(n0 + t) * 4);
    *(float4*)&sx[t * 4] = xv;
  }
  __syncthreads();

  for (int i = t; i < nb; i += 256) atomicAdd(&cnt[ebuf[base + i] >> 17], 1);
  __syncthreads();
  if (t < 64) {
    int v = cnt[t];
    int incl = v;
#pragma unroll
    for (int off = 1; off < 64; off <<= 1) {
      int nvv = __shfl_up(incl, off);
      if (t >= off) incl += nvv;
    }
    int excl = incl - v;
    start[t] = excl;
    cnt[t] = excl;          // becomes fill cursor
    if (n0 + t < N_NODES) row_start[n0 + t] = base + excl;
  }
  __syncthreads();
  for (int i = t; i < nb; i += 256) {
    unsigned e = ebuf[base + i];
    int p = atomicAdd(&cnt[e >> 17], 1);
    csr_src[base + p] = (int)(e & 0x1FFFFu);
  }
  __syncthreads();
  {
    int nd = t >> 2, sub = t & 3;
    int rs = base + start[nd];
    int re = base + cnt[nd];
    float4 acc = make_float4(0.f, 0.f, 0.f, 0.f);
    for (int i = rs + sub; i < re; i += 4) {
      int s = csr_src[i];
      float4 v = *(const float4*)(x + (size_t)s * 4);
      acc.x += v.x; acc.y += v.y; acc.z += v.z; acc.w += v.w;
    }
#pragma unroll
    for (int off = 1; off < 4; off <<= 1) {
      acc.x += __shfl_xor(acc.x, off);
      acc.y += __shfl_xor(acc.y, off);
      acc.z += __shfl_xor(acc.z, off);
      acc.w += __shfl_xor(acc.w, off);
    }
    if (sub == 0) *(float4*)&sagg[nd * 4] = acc;
    if (t < 64 && n0 + t < N_NODES) row_end[n0 + t] = base + cnt[t];
  }
  __syncthreads();

  for (int it = t; it < BUCK_NODES * 64; it += 256) {
    int nd = it >> 6;
    if (n0 + nd >= N_NODES) break;
    int fp = it & 63;
    int f = fp * 2;
    float4 a  = *(float4*)&sagg[nd * 4];
    float4 xv = *(float4*)&sx[nd * 4];
    float v0 = sb1[f]
        + a.x  * sWa[0 * 128 + f] + a.y  * sWa[1 * 128 + f]
        + a.z  * sWa[2 * 128 + f] + a.w  * sWa[3 * 128 + f]
        + xv.x * sWa[4 * 128 + f] + xv.y * sWa[5 * 128 + f]
        + xv.z * sWa[6 * 128 + f] + xv.w * sWa[7 * 128 + f];
    int f1 = f + 1;
    float v1 = sb1[f1]
        + a.x  * sWa[0 * 128 + f1] + a.y  * sWa[1 * 128 + f1]
        + a.z  * sWa[2 * 128 + f1] + a.w  * sWa[3 * 128 + f1]
        + xv.x * sWa[4 * 128 + f1] + xv.y * sWa[5 * 128 + f1]
        + xv.z * sWa[6 * 128 + f1] + xv.w * sWa[7 * 128 + f1];
    float r0 = fmaxf(v0, 0.f), r1 = fmaxf(v1, 0.f);
    h1f8[(size_t)(n0 + nd) * 64 + fp] =
        (unsigned short)__builtin_amdgcn_cvt_pk_fp8_f32(r0, r1, 0, false);
  }
}

// ============ layer 2 aggregate: split-wave paired FP8 gather ============
__global__ __launch_bounds__(256) void k_pull128(
    const unsigned* __restrict__ h1f8_u, const int* __restrict__ row_start,
    const int* __restrict__ row_end, const int* __restrict__ csr_src,
    uint2* __restrict__ agg2b) {
  int w = (blockIdx.x * 256 + threadIdx.x) >> 6;
  if (w >= N_NODES) return;
  int lane = threadIdx.x & 63;
  int half = lane >> 5;     // which edge of the pair
  int hl = lane & 31;       // feature-quad index: features 4*hl..4*hl+3
  int rs = row_start[w], re = row_end[w];
  float a0 = 0.f, a1 = 0.f, a2 = 0.f, a3 = 0.f;
  for (int chunk = rs; chunk < re; chunk += 64) {
    int nv = min(64, re - chunk);
    int sv = (chunk + lane < re) ? csr_src[chunk + lane] : 0;
    int j = 0;
    for (; j + 8 <= nv; j += 8) {       // 4 pair-loads in flight (8 edges)
      int s0 = __shfl(sv, j + 0 + half);
      int s1 = __shfl(sv, j + 2 + half);
      int s2 = __shfl(sv, j + 4 + half);
      int s3 = __shfl(sv, j + 6 + half);
      unsigned u0 = h1f8_u[(size_t)s0 * 32 + hl];
      unsigned u1 = h1f8_u[(size_t)s1 * 32 + hl];
      unsigned u2 = h1f8_u[(size_t)s2 * 32 + hl];
      unsigned u3 = h1f8_u[(size_t)s3 * 32 + hl];
      f32x2 l0 = __builtin_amdgcn_cvt_pk_f32_fp8((int)u0, false);
      f32x2 h0 = __builtin_amdgcn_cvt_pk_f32_fp8((int)u0, true);
      f32x2 l1 = __builtin_amdgcn_cvt_pk_f32_fp8((int)u1, false);
      f32x2 h1 = __builtin_amdgcn_cvt_pk_f32_fp8((int)u1, true);
      f32x2 l2 = __builtin_amdgcn_cvt_pk_f32_fp8((int)u2, false);
      f32x2 h2 = __builtin_amdgcn_cvt_pk_f32_fp8((int)u2, true);
      f32x2 l3 = __builtin_amdgcn_cvt_pk_f32_fp8((int)u3, false);
      f32x2 h3 = __builtin_amdgcn_cvt_pk_f32_fp8((int)u3, true);
      a0 += l0.x + l1.x + l2.x + l3.x;
      a1 += l0.y + l1.y + l2.y + l3.y;
      a2 += h0.x + h1.x + h2.x + h3.x;
      a3 += h0.y + h1.y + h2.y + h3.y;
    }
    for (; j + 2 <= nv; j += 2) {       // paired tail
      int s0 = __shfl(sv, j + half);
      unsigned u0 = h1f8_u[(size_t)s0 * 32 + hl];
      f32x2 l0 = __builtin_amdgcn_cvt_pk_f32_fp8((int)u0, false);
      f32x2 h0 = __builtin_amdgcn_cvt_pk_f32_fp8((int)u0, true);
      a0 += l0.x; a1 += l0.y; a2 += h0.x; a3 += h0.y;
    }
    if (j < nv) {                        // odd single: half 0 only
      int s0 = __shfl(sv, j);
      unsigned u0 = h1f8_u[(size_t)s0 * 32 + hl];
      if (half == 0) {
        f32x2 l0 = __builtin_amdgcn_cvt_pk_f32_fp8((int)u0, false);
        f32x2 h0 = __builtin_amdgcn_cvt_pk_f32_fp8((int)u0, true);
        a0 += l0.x; a1 += l0.y; a2 += h0.x; a3 += h0.y;
      }
    }
  }
  a0 += __shfl_xor(a0, 32);
  a1 += __shfl_xor(a1, 32);
  a2 += __shfl_xor(a2, 32);
  a3 += __shfl_xor(a3, 32);
  if (half == 0) {
    uint2 o;
    o.x = pack_bf16x2(a0, a1);
    o.y = pack_bf16x2(a2, a3);
    agg2b[(size_t)w * 32 + hl] = o;
  }
}

// ====== layer 2 dense + pool: MFMA GEMM, 32-node waves (no fused head) ======
// R13's fused head regressed this kernel 40->64 us (__threadfence per wave +
// serialized done-atomics). Reverted to standalone k_final.
__global__ __launch_bounds__(256) void k_gemm_pool(
    const unsigned* __restrict__ agg2b_u, const unsigned short* __restrict__ h1f8,
    const unsigned* __restrict__ wbuf_u, const float* __restrict__ b2,
    float* __restrict__ gsum) {
  __shared__ float lgs[128];
  int t = threadIdx.x;
  if (t < 128) lgs[t] = 0.0f;
  __syncthreads();

  int lane = t & 63;
  int gw = blockIdx.x * 4 + (t >> 6);
  int lrow = lane & 15;
  int quad = lane >> 4;
  const unsigned short* agg2b = (const unsigned short*)agg2b_u;
  const unsigned char* h8 = (const unsigned char*)h1f8;
  const short8* wb = (const short8*)wbuf_u;

  float bias[8];
#pragma unroll
  for (int tt = 0; tt < 8; ++tt) bias[tt] = b2[tt * 16 + lrow];
  float csum[8] = {0.f, 0.f, 0.f, 0.f, 0.f, 0.f, 0.f, 0.f};

  if (gw < NCHUNK32) {
    int mbase = gw * 32;

    f32x4 acc[2][8];
#pragma unroll
    for (int mt = 0; mt < 2; ++mt)
#pragma unroll
      for (int tt = 0; tt < 8; ++tt) acc[mt][tt] = (f32x4){0.f, 0.f, 0.f, 0.f};

#pragma unroll
    for (int ks = 0; ks < 4; ++ks) {
      const unsigned short* abase = agg2b + ks * 32 + quad * 8;
      short8 afr[2];
#pragma unroll
      for (int mt = 0; mt < 2; ++mt)
        afr[mt] = *(const short8*)(abase + (size_t)(mbase + mt * 16 + lrow) * 128);
      short8 bfr[8];
#pragma unroll
      for (int tt = 0; tt < 8; ++tt) bfr[tt] = wb[(ks * 8 + tt) * 64 + lane];
#pragma unroll
      for (int mt = 0; mt < 2; ++mt)
#pragma unroll
        for (int tt = 0; tt < 8; ++tt)
          acc[mt][tt] = __builtin_amdgcn_mfma_f32_16x16x32_bf16(
              afr[mt], bfr[tt], acc[mt][tt], 0, 0, 0);
    }
#pragma unroll
    for (int ks = 4; ks < 8; ++ks) {
      short8 afr[2];
#pragma unroll
      for (int mt = 0; mt < 2; ++mt) {
        const uint2* ap = (const uint2*)(h8 + (size_t)(mbase + mt * 16 + lrow) * 128
                                         + (ks - 4) * 32 + quad * 8);
        uint2 u = *ap;
        f32x2 a0 = __builtin_amdgcn_cvt_pk_f32_fp8((int)u.x, false);
        f32x2 a1 = __builtin_amdgcn_cvt_pk_f32_fp8((int)u.x, true);
        f32x2 a2 = __builtin_amdgcn_cvt_pk_f32_fp8((int)u.y, false);
        f32x2 a3 = __builtin_amdgcn_cvt_pk_f32_fp8((int)u.y, true);
        unsigned q[4] = {pack_bf16x2(a0.x, a0.y), pack_bf16x2(a1.x, a1.y),
                         pack_bf16x2(a2.x, a2.y), pack_bf16x2(a3.x, a3.y)};
        afr[mt] = *(short8*)q;
      }
      short8 bfr[8];
#pragma unroll
      for (int tt = 0; tt < 8; ++tt) bfr[tt] = wb[(ks * 8 + tt) * 64 + lane];
#pragma unroll
      for (int mt = 0; mt < 2; ++mt)
#pragma unroll
        for (int tt = 0; tt < 8; ++tt)
          acc[mt][tt] = __builtin_amdgcn_mfma_f32_16x16x32_bf16(
              afr[mt], bfr[tt], acc[mt][tt], 0, 0, 0);
    }

#pragma unroll
    for (int mt = 0; mt < 2; ++mt) {
#pragma unroll
      for (int tt = 0; tt < 8; ++tt) {
        f32x4 v = acc[mt][tt];
        float s = fmaxf(v.x + bias[tt], 0.f) + fmaxf(v.y + bias[tt], 0.f)
                + fmaxf(v.z + bias[tt], 0.f) + fmaxf(v.w + bias[tt], 0.f);
        s += __shfl_xor(s, 16);
        s += __shfl_xor(s, 32);
        csum[tt] += s;
      }
    }
  }
  if (lane < 16) {
#pragma unroll
    for (int tt = 0; tt < 8; ++tt) atomicAdd(&lgs[tt * 16 + lane], csum[tt]);
  }
  __syncthreads();
  if (t < 128) atomicAdd(&gsum[t], lgs[t]);
}

// ============ head: out = (gsum/N) @ Wlin.T + blin ============
__global__ void k_final(const float* __restrict__ gsum, const float* __restrict__ Wlin,
                        const float* __restrict__ blin, float* __restrict__ out) {
  int lane = threadIdx.x;  // 64 threads
  float g0 = gsum[lane];
  float g1 = gsum[lane + 64];
  float s0 = g0 * Wlin[lane]       + g1 * Wlin[lane + 64];
  float s1 = g0 * Wlin[128 + lane] + g1 * Wlin[192 + lane];
#pragma unroll
  for (int off = 32; off > 0; off >>= 1) {
    s0 += __shfl_down(s0, off);
    s1 += __shfl_down(s1, off);
  }
  if (lane == 0) {
    const float inv = 1.0f / (float)N_NODES;
    out[0] = s0 * inv + blin[0];
    out[1] = s1 * inv + blin[1];
  }
}

extern "C" void kernel_launch(void* const* d_in, const int* in_sizes, int n_in,
                              void* d_out, int out_size, void* d_ws, size_t ws_size,
                              hipStream_t stream) {
  const float* x       = (const float*)d_in[0];
  const int*   ei      = (const int*)d_in[1];
  const float* W1_rel  = (const float*)d_in[2];
  const float* b1      = (const float*)d_in[3];
  const float* W1_root = (const float*)d_in[4];
  const float* W2_rel  = (const float*)d_in[5];
  const float* b2      = (const float*)d_in[6];
  const float* W2_root = (const float*)d_in[7];
  const float* Wlin    = (const float*)d_in[8];
  const float* blin    = (const float*)d_in[9];
  const int* src = ei;            // edge_index[0]
  const int* dst = ei + N_EDGES;  // edge_index[1]
  float* out = (float*)d_out;

  // workspace layout (bytes):
  //   row_start     @0          : 400,000
  //   row_end       @400,000    : 400,000
  //   bucket_cursor @800,000    : 8,192
  //   gsum          @808,192    : 512
  //   wbuf          @808,832    : 65,536     -> 874,368
  //   csr_src       @874,368    : 9,603,072  -> 10,477,440
  //   ebuf (uint)   @10,477,440 : 9,603,072  -> 20,080,512
  //   h1f8 (fp8)    @20,080,512 : 12,800,000 -> 32,880,512
  //   agg2b (bf16)  @32,880,512 : 25,600,000 -> 58,480,512
  char* ws = (char*)d_ws;
  int*            row_start     = (int*)(ws);
  int*            row_end       = (int*)(ws + 400000);
  int*            bucket_cursor = (int*)(ws + 800000);
  float*          gsum          = (float*)(ws + 808192);
  unsigned*       wbuf          = (unsigned*)(ws + 808832);
  int*            csr_src       = (int*)(ws + 874368);
  unsigned*       ebuf          = (unsigned*)(ws + 10477440);
  unsigned short* h1f8          = (unsigned short*)(ws + 20080512);
  uint2*          agg2b         = (uint2*)(ws + 32880512);

  k_init <<<1, 512, 0, stream>>>(bucket_cursor, gsum, W2_rel, W2_root, wbuf);
  k_bfill<<<BF_BLOCKS, 512, 0, stream>>>(src, dst, bucket_cursor, ebuf);
  k_fill2<<<NBUCK, 256, 0, stream>>>(ebuf, bucket_cursor, x, W1_rel, b1, W1_root,
                                     row_start, row_end, csr_src, h1f8);
  k_pull128<<<(N_NODES * 64 + 255) / 256, 256, 0, stream>>>(
      (const unsigned*)h1f8, row_start, row_end, csr_src, agg2b);
  k_gemm_pool<<<GEMM_BLOCKS, 256, 0, stream>>>(
      (const unsigned*)agg2b, h1f8, wbuf, b2, gsum);
  k_final<<<1, 64, 0, stream>>>(gsum, Wlin, blin, out);
}

// Round 15
// 200.546 us; speedup vs baseline: 1.1611x; 1.0186x over previous
//
#include <hip/hip_runtime.h>
#include <cstddef>

#define N_NODES 100000
#define N_EDGES 1600000
#define NCHUNK32 3125   // N_NODES / 32, exact
#define GEMM_BLOCKS ((NCHUNK32 + 3) / 4)      // 782
#define BUCK_SHIFT 6
#define BUCK_NODES 64                         // nodes per bucket (pow2: no div)
#define NBUCK 1563                            // ceil(N_NODES / 64)
#define EB_CAP 1536     // mean 1024, sigma ~32 -> +16 sigma
#define BF_EDGES 8192
#define BF_BLOCKS ((N_EDGES + BF_EDGES - 1) / BF_EDGES)   // 196

typedef __attribute__((ext_vector_type(8))) short short8;   // 8 bf16 = 4 VGPRs
typedef __attribute__((ext_vector_type(4))) float f32x4;
typedef __attribute__((ext_vector_type(2))) float f32x2;

__device__ __forceinline__ unsigned pack_bf16x2(float a, float b) {
  unsigned ua = __float_as_uint(a); ua += 0x7FFFu + ((ua >> 16) & 1u);
  unsigned ub = __float_as_uint(b); ub += 0x7FFFu + ((ub >> 16) & 1u);
  return (ua >> 16) | (ub & 0xFFFF0000u);
}

// ====== init: cursors + gsum + fragment-ordered W2 buffer ======
__global__ __launch_bounds__(512) void k_init(int* __restrict__ bucket_cursor,
                                              float* __restrict__ gsum,
                                              const float* __restrict__ W2_rel,
                                              const float* __restrict__ W2_root,
                                              unsigned* __restrict__ wbuf) {
  int t = threadIdx.x;
  for (int b = t; b < NBUCK; b += 512) bucket_cursor[b] = b * EB_CAP;
  if (t < 128) gsum[t] = 0.0f;
#pragma unroll
  for (int i = 0; i < 8; ++i) {
    int e = t + i * 512;                    // 0..4095
    int L = e & 63, T = (e >> 6) & 7, K0 = e >> 9;
    int f = T * 16 + (L & 15);
    int k0 = K0 * 32 + ((L >> 4) << 3);     // 8-aligned; never crosses 128
    const float* wsrc = (k0 < 128) ? (W2_rel + f * 128 + k0)
                                   : (W2_root + f * 128 + (k0 - 128));
    float4 w0 = *(const float4*)(wsrc);
    float4 w1 = *(const float4*)(wsrc + 4);
    unsigned* d = wbuf + e * 4;
    d[0] = pack_bf16x2(w0.x, w0.y);
    d[1] = pack_bf16x2(w0.z, w0.w);
    d[2] = pack_bf16x2(w1.x, w1.y);
    d[3] = pack_bf16x2(w1.z, w1.w);
  }
}

// ============ CSR build pass 1: bucket-scatter packed edges ============
// packed edge = (dst_local << 17) | src. int4 loads: 4 edges/load.
__global__ __launch_bounds__(512) void k_bfill(const int* __restrict__ src,
                                               const int* __restrict__ dst,
                                               int* __restrict__ bucket_cursor,
                                               unsigned* __restrict__ ebuf) {
  __shared__ int lh[NBUCK];
  __shared__ int sub_base[NBUCK];
  __shared__ int cur[NBUCK];
  int t = threadIdx.x;
  for (int b = t; b < NBUCK; b += 512) { lh[b] = 0; cur[b] = 0; }
  __syncthreads();
  int e0 = blockIdx.x * BF_EDGES;
  unsigned pk[16];
  int bk[16];
#pragma unroll
  for (int i = 0; i < 4; ++i) {
    int e = e0 + (i * 512 + t) * 4;
    if (e + 4 <= N_EDGES) {
      int4 s4 = *(const int4*)(src + e);
      int4 d4 = *(const int4*)(dst + e);
      int dd[4] = {d4.x, d4.y, d4.z, d4.w};
      int ss[4] = {s4.x, s4.y, s4.z, s4.w};
#pragma unroll
      for (int j = 0; j < 4; ++j) {
        int b = dd[j] >> BUCK_SHIFT;
        bk[i * 4 + j] = b;
        pk[i * 4 + j] = ((unsigned)(dd[j] & (BUCK_NODES - 1)) << 17) | (unsigned)ss[j];
        atomicAdd(&lh[b], 1);
      }
    } else {
#pragma unroll
      for (int j = 0; j < 4; ++j) {
        bk[i * 4 + j] = -1;
        if (e + j < N_EDGES) {
          int d = dst[e + j];
          int b = d >> BUCK_SHIFT;
          bk[i * 4 + j] = b;
          pk[i * 4 + j] = ((unsigned)(d & (BUCK_NODES - 1)) << 17) | (unsigned)src[e + j];
          atomicAdd(&lh[b], 1);
        }
      }
    }
  }
  __syncthreads();
  for (int b = t; b < NBUCK; b += 512)
    sub_base[b] = (lh[b] > 0) ? atomicAdd(&bucket_cursor[b], lh[b]) : 0;
  __syncthreads();
#pragma unroll
  for (int i = 0; i < 16; ++i) {
    if (bk[i] >= 0) {
      int pos = sub_base[bk[i]] + atomicAdd(&cur[bk[i]], 1);
      if (pos < (bk[i] + 1) * EB_CAP) ebuf[pos] = pk[i];  // +16 sigma guard
    }
  }
}

// ====== CSR build pass 2 + layer-1 (fused): one block per 64-node bucket ====
__global__ __launch_bounds__(256) void k_fill2(
    const unsigned* __restrict__ ebuf, const int* __restrict__ bucket_cursor,
    const float* __restrict__ x, const float* __restrict__ W1_rel,
    const float* __restrict__ b1, const float* __restrict__ W1_root,
    int2* __restrict__ row_se, int* __restrict__ csr_src,
    unsigned short* __restrict__ h1f8) {
  __shared__ int cnt[BUCK_NODES];
  __shared__ int start[BUCK_NODES];
  __shared__ float sagg[BUCK_NODES * 4];
  __shared__ float sx[BUCK_NODES * 4];
  __shared__ float sWa[8 * 128];
  __shared__ float sb1[128];
  int t = threadIdx.x;
  int b = blockIdx.x;
  int base = b * EB_CAP;
  int nb = bucket_cursor[b] - base;
  if (nb > EB_CAP) nb = EB_CAP;
  int n0 = b << BUCK_SHIFT;

  if (t < 128) {
    float4 wr = *(const float4*)(W1_rel + t * 4);
    float4 wo = *(const float4*)(W1_root + t * 4);
    sWa[0 * 128 + t] = wr.x; sWa[1 * 128 + t] = wr.y;
    sWa[2 * 128 + t] = wr.z; sWa[3 * 128 + t] = wr.w;
    sWa[4 * 128 + t] = wo.x; sWa[5 * 128 + t] = wo.y;
    sWa[6 * 128 + t] = wo.z; sWa[7 * 128 + t] = wo.w;
    sb1[t] = b1[t];
  }
  if (t < BUCK_NODES) {
    cnt[t] = 0;
    float4 xv = make_float4(0.f, 0.f, 0.f, 0.f);
    if (n0 + t < N_NODES) xv = *(const float4*)(x + (size_t)(n0 + t) * 4);
    *(float4*)&sx[t * 4] = xv;
  }
  __syncthreads();

  for (int i = t; i < nb; i += 256) atomicAdd(&cnt[ebuf[base + i] >> 17], 1);
  __syncthreads();
  if (t < 64) {
    int v = cnt[t];
    int incl = v;
#pragma unroll
    for (int off = 1; off < 64; off <<= 1) {
      int nvv = __shfl_up(incl, off);
      if (t >= off) incl += nvv;
    }
    int excl = incl - v;
    start[t] = excl;
    cnt[t] = excl;          // becomes fill cursor
  }
  __syncthreads();
  for (int i = t; i < nb; i += 256) {
    unsigned e = ebuf[base + i];
    int p = atomicAdd(&cnt[e >> 17], 1);
    csr_src[base + p] = (int)(e & 0x1FFFFu);
  }
  __syncthreads();
  {
    int nd = t >> 2, sub = t & 3;
    int rs = base + start[nd];
    int re = base + cnt[nd];
    float4 acc = make_float4(0.f, 0.f, 0.f, 0.f);
    for (int i = rs + sub; i < re; i += 4) {
      int s = csr_src[i];
      float4 v = *(const float4*)(x + (size_t)s * 4);
      acc.x += v.x; acc.y += v.y; acc.z += v.z; acc.w += v.w;
    }
#pragma unroll
    for (int off = 1; off < 4; off <<= 1) {
      acc.x += __shfl_xor(acc.x, off);
      acc.y += __shfl_xor(acc.y, off);
      acc.z += __shfl_xor(acc.z, off);
      acc.w += __shfl_xor(acc.w, off);
    }
    if (sub == 0) *(float4*)&sagg[nd * 4] = acc;
    if (t < 64 && n0 + t < N_NODES)
      row_se[n0 + t] = make_int2(base + start[t], base + cnt[t]);
  }
  __syncthreads();

  for (int it = t; it < BUCK_NODES * 64; it += 256) {
    int nd = it >> 6;
    if (n0 + nd >= N_NODES) break;
    int fp = it & 63;
    int f = fp * 2;
    float4 a  = *(float4*)&sagg[nd * 4];
    float4 xv = *(float4*)&sx[nd * 4];
    float v0 = sb1[f]
        + a.x  * sWa[0 * 128 + f] + a.y  * sWa[1 * 128 + f]
        + a.z  * sWa[2 * 128 + f] + a.w  * sWa[3 * 128 + f]
        + xv.x * sWa[4 * 128 + f] + xv.y * sWa[5 * 128 + f]
        + xv.z * sWa[6 * 128 + f] + xv.w * sWa[7 * 128 + f];
    int f1 = f + 1;
    float v1 = sb1[f1]
        + a.x  * sWa[0 * 128 + f1] + a.y  * sWa[1 * 128 + f1]
        + a.z  * sWa[2 * 128 + f1] + a.w  * sWa[3 * 128 + f1]
        + xv.x * sWa[4 * 128 + f1] + xv.y * sWa[5 * 128 + f1]
        + xv.z * sWa[6 * 128 + f1] + xv.w * sWa[7 * 128 + f1];
    float r0 = fmaxf(v0, 0.f), r1 = fmaxf(v1, 0.f);
    h1f8[(size_t)(n0 + nd) * 64 + fp] =
        (unsigned short)__builtin_amdgcn_cvt_pk_fp8_f32(r0, r1, 0, false);
  }
}

// ---- single-node chunk gather (fallback for degree > 64; practically cold) ----
__device__ __forceinline__ void gather_chunk(
    const unsigned* __restrict__ h, const int* __restrict__ csr,
    int chunk, int re, int lane, int half, int hl,
    float& a0, float& a1, float& a2, float& a3) {
  int nv = min(64, re - chunk);
  int sv = (chunk + lane < re) ? csr[chunk + lane] : 0;
  int j = 0;
  for (; j + 2 <= nv; j += 2) {
    int s0 = __shfl(sv, j + half);
    unsigned u0 = h[(size_t)s0 * 32 + hl];
    f32x2 l0 = __builtin_amdgcn_cvt_pk_f32_fp8((int)u0, false);
    f32x2 h0 = __builtin_amdgcn_cvt_pk_f32_fp8((int)u0, true);
    a0 += l0.x; a1 += l0.y; a2 += h0.x; a3 += h0.y;
  }
  if (j < nv) {
    int s0 = __shfl(sv, j);
    unsigned u0 = h[(size_t)s0 * 32 + hl];
    if (half == 0) {
      f32x2 l0 = __builtin_amdgcn_cvt_pk_f32_fp8((int)u0, false);
      f32x2 h0 = __builtin_amdgcn_cvt_pk_f32_fp8((int)u0, true);
      a0 += l0.x; a1 += l0.y; a2 += h0.x; a3 += h0.y;
    }
  }
}

// ============ layer 2 aggregate: TWO nodes per wave, paired FP8 gather ======
// Mean degree 16 => whole row fits one 64-edge chunk; two independent gather
// chains per wave (8 loads in flight) hide L2/L3 latency twice as deep.
__global__ __launch_bounds__(256) void k_pull128(
    const unsigned* __restrict__ h1f8_u, const int2* __restrict__ row_se,
    const int* __restrict__ csr_src, uint2* __restrict__ agg2b) {
  int gw = (blockIdx.x * 256 + threadIdx.x) >> 6;
  int w0 = gw * 2;
  if (w0 >= N_NODES) return;
  int w1 = w0 + 1;                 // N_NODES even
  int lane = threadIdx.x & 63;
  int half = lane >> 5;
  int hl = lane & 31;
  int2 se0 = row_se[w0];
  int2 se1 = row_se[w1];
  int nv0 = min(64, se0.y - se0.x);
  int nv1 = min(64, se1.y - se1.x);
  int sv0 = (se0.x + lane < se0.y) ? csr_src[se0.x + lane] : 0;
  int sv1 = (se1.x + lane < se1.y) ? csr_src[se1.x + lane] : 0;
  float a0 = 0.f, a1 = 0.f, a2 = 0.f, a3 = 0.f;   // node w0
  float c0 = 0.f, c1 = 0.f, c2 = 0.f, c3 = 0.f;   // node w1
  int j0 = 0, j1 = 0;
  // joint main loop: 8 independent gathers in flight (4 per node)
  while (j0 + 8 <= nv0 && j1 + 8 <= nv1) {
    int s00 = __shfl(sv0, j0 + 0 + half);
    int s01 = __shfl(sv0, j0 + 2 + half);
    int s02 = __shfl(sv0, j0 + 4 + half);
    int s03 = __shfl(sv0, j0 + 6 + half);
    int s10 = __shfl(sv1, j1 + 0 + half);
    int s11 = __shfl(sv1, j1 + 2 + half);
    int s12 = __shfl(sv1, j1 + 4 + half);
    int s13 = __shfl(sv1, j1 + 6 + half);
    unsigned u00 = h1f8_u[(size_t)s00 * 32 + hl];
    unsigned u01 = h1f8_u[(size_t)s01 * 32 + hl];
    unsigned u02 = h1f8_u[(size_t)s02 * 32 + hl];
    unsigned u03 = h1f8_u[(size_t)s03 * 32 + hl];
    unsigned u10 = h1f8_u[(size_t)s10 * 32 + hl];
    unsigned u11 = h1f8_u[(size_t)s11 * 32 + hl];
    unsigned u12 = h1f8_u[(size_t)s12 * 32 + hl];
    unsigned u13 = h1f8_u[(size_t)s13 * 32 + hl];
    f32x2 l00 = __builtin_amdgcn_cvt_pk_f32_fp8((int)u00, false);
    f32x2 h00 = __builtin_amdgcn_cvt_pk_f32_fp8((int)u00, true);
    f32x2 l01 = __builtin_amdgcn_cvt_pk_f32_fp8((int)u01, false);
    f32x2 h01 = __builtin_amdgcn_cvt_pk_f32_fp8((int)u01, true);
    f32x2 l02 = __builtin_amdgcn_cvt_pk_f32_fp8((int)u02, false);
    f32x2 h02 = __builtin_amdgcn_cvt_pk_f32_fp8((int)u02, true);
    f32x2 l03 = __builtin_amdgcn_cvt_pk_f32_fp8((int)u03, false);
    f32x2 h03 = __builtin_amdgcn_cvt_pk_f32_fp8((int)u03, true);
    a0 += l00.x + l01.x + l02.x + l03.x;
    a1 += l00.y + l01.y + l02.y + l03.y;
    a2 += h00.x + h01.x + h02.x + h03.x;
    a3 += h00.y + h01.y + h02.y + h03.y;
    f32x2 l10 = __builtin_amdgcn_cvt_pk_f32_fp8((int)u10, false);
    f32x2 h10 = __builtin_amdgcn_cvt_pk_f32_fp8((int)u10, true);
    f32x2 l11 = __builtin_amdgcn_cvt_pk_f32_fp8((int)u11, false);
    f32x2 h11 = __builtin_amdgcn_cvt_pk_f32_fp8((int)u11, true);
    f32x2 l12 = __builtin_amdgcn_cvt_pk_f32_fp8((int)u12, false);
    f32x2 h12 = __builtin_amdgcn_cvt_pk_f32_fp8((int)u12, true);
    f32x2 l13 = __builtin_amdgcn_cvt_pk_f32_fp8((int)u13, false);
    f32x2 h13 = __builtin_amdgcn_cvt_pk_f32_fp8((int)u13, true);
    c0 += l10.x + l11.x + l12.x + l13.x;
    c1 += l10.y + l11.y + l12.y + l13.y;
    c2 += h10.x + h11.x + h12.x + h13.x;
    c3 += h10.y + h11.y + h12.y + h13.y;
    j0 += 8; j1 += 8;
  }
  // node0 tail
  for (; j0 + 2 <= nv0; j0 += 2) {
    int s0 = __shfl(sv0, j0 + half);
    unsigned u0 = h1f8_u[(size_t)s0 * 32 + hl];
    f32x2 l0 = __builtin_amdgcn_cvt_pk_f32_fp8((int)u0, false);
    f32x2 h0 = __builtin_amdgcn_cvt_pk_f32_fp8((int)u0, true);
    a0 += l0.x; a1 += l0.y; a2 += h0.x; a3 += h0.y;
  }
  if (j0 < nv0) {
    int s0 = __shfl(sv0, j0);
    unsigned u0 = h1f8_u[(size_t)s0 * 32 + hl];
    if (half == 0) {
      f32x2 l0 = __builtin_amdgcn_cvt_pk_f32_fp8((int)u0, false);
      f32x2 h0 = __builtin_amdgcn_cvt_pk_f32_fp8((int)u0, true);
      a0 += l0.x; a1 += l0.y; a2 += h0.x; a3 += h0.y;
    }
  }
  // node1 tail
  for (; j1 + 2 <= nv1; j1 += 2) {
    int s0 = __shfl(sv1, j1 + half);
    unsigned u0 = h1f8_u[(size_t)s0 * 32 + hl];
    f32x2 l0 = __builtin_amdgcn_cvt_pk_f32_fp8((int)u0, false);
    f32x2 h0 = __builtin_amdgcn_cvt_pk_f32_fp8((int)u0, true);
    c0 += l0.x; c1 += l0.y; c2 += h0.x; c3 += h0.y;
  }
  if (j1 < nv1) {
    int s0 = __shfl(sv1, j1);
    unsigned u0 = h1f8_u[(size_t)s0 * 32 + hl];
    if (half == 0) {
      f32x2 l0 = __builtin_amdgcn_cvt_pk_f32_fp8((int)u0, false);
      f32x2 h0 = __builtin_amdgcn_cvt_pk_f32_fp8((int)u0, true);
      c0 += l0.x; c1 += l0.y; c2 += h0.x; c3 += h0.y;
    }
  }
  // rare overflow chunks (degree > 64)
  for (int chunk = se0.x + 64; chunk < se0.y; chunk += 64)
    gather_chunk(h1f8_u, csr_src, chunk, se0.y, lane, half, hl, a0, a1, a2, a3);
  for (int chunk = se1.x + 64; chunk < se1.y; chunk += 64)
    gather_chunk(h1f8_u, csr_src, chunk, se1.y, lane, half, hl, c0, c1, c2, c3);

  a0 += __shfl_xor(a0, 32);
  a1 += __shfl_xor(a1, 32);
  a2 += __shfl_xor(a2, 32);
  a3 += __shfl_xor(a3, 32);
  c0 += __shfl_xor(c0, 32);
  c1 += __shfl_xor(c1, 32);
  c2 += __shfl_xor(c2, 32);
  c3 += __shfl_xor(c3, 32);
  if (half == 0) {
    uint2 o0, o1;
    o0.x = pack_bf16x2(a0, a1);
    o0.y = pack_bf16x2(a2, a3);
    o1.x = pack_bf16x2(c0, c1);
    o1.y = pack_bf16x2(c2, c3);
    agg2b[(size_t)w0 * 32 + hl] = o0;
    agg2b[(size_t)w1 * 32 + hl] = o1;
  }
}

// ====== layer 2 dense + pool: MFMA GEMM, 32-node waves ======
__global__ __launch_bounds__(256) void k_gemm_pool(
    const unsigned* __restrict__ agg2b_u, const unsigned short* __restrict__ h1f8,
    const unsigned* __restrict__ wbuf_u, const float* __restrict__ b2,
    float* __restrict__ gsum) {
  __shared__ float lgs[128];
  int t = threadIdx.x;
  if (t < 128) lgs[t] = 0.0f;
  __syncthreads();

  int lane = t & 63;
  int gw = blockIdx.x * 4 + (t >> 6);
  int lrow = lane & 15;
  int quad = lane >> 4;
  const unsigned short* agg2b = (const unsigned short*)agg2b_u;
  const unsigned char* h8 = (const unsigned char*)h1f8;
  const short8* wb = (const short8*)wbuf_u;

  float bias[8];
#pragma unroll
  for (int tt = 0; tt < 8; ++tt) bias[tt] = b2[tt * 16 + lrow];
  float csum[8] = {0.f, 0.f, 0.f, 0.f, 0.f, 0.f, 0.f, 0.f};

  if (gw < NCHUNK32) {
    int mbase = gw * 32;

    f32x4 acc[2][8];
#pragma unroll
    for (int mt = 0; mt < 2; ++mt)
#pragma unroll
      for (int tt = 0; tt < 8; ++tt) acc[mt][tt] = (f32x4){0.f, 0.f, 0.f, 0.f};

#pragma unroll
    for (int ks = 0; ks < 4; ++ks) {
      const unsigned short* abase = agg2b + ks * 32 + quad * 8;
      short8 afr[2];
#pragma unroll
      for (int mt = 0; mt < 2; ++mt)
        afr[mt] = *(const short8*)(abase + (size_t)(mbase + mt * 16 + lrow) * 128);
      short8 bfr[8];
#pragma unroll
      for (int tt = 0; tt < 8; ++tt) bfr[tt] = wb[(ks * 8 + tt) * 64 + lane];
#pragma unroll
      for (int mt = 0; mt < 2; ++mt)
#pragma unroll
        for (int tt = 0; tt < 8; ++tt)
          acc[mt][tt] = __builtin_amdgcn_mfma_f32_16x16x32_bf16(
              afr[mt], bfr[tt], acc[mt][tt], 0, 0, 0);
    }
#pragma unroll
    for (int ks = 4; ks < 8; ++ks) {
      short8 afr[2];
#pragma unroll
      for (int mt = 0; mt < 2; ++mt) {
        const uint2* ap = (const uint2*)(h8 + (size_t)(mbase + mt * 16 + lrow) * 128
                                         + (ks - 4) * 32 + quad * 8);
        uint2 u = *ap;
        f32x2 a0 = __builtin_amdgcn_cvt_pk_f32_fp8((int)u.x, false);
        f32x2 a1 = __builtin_amdgcn_cvt_pk_f32_fp8((int)u.x, true);
        f32x2 a2 = __builtin_amdgcn_cvt_pk_f32_fp8((int)u.y, false);
        f32x2 a3 = __builtin_amdgcn_cvt_pk_f32_fp8((int)u.y, true);
        unsigned q[4] = {pack_bf16x2(a0.x, a0.y), pack_bf16x2(a1.x, a1.y),
                         pack_bf16x2(a2.x, a2.y), pack_bf16x2(a3.x, a3.y)};
        afr[mt] = *(short8*)q;
      }
      short8 bfr[8];
#pragma unroll
      for (int tt = 0; tt < 8; ++tt) bfr[tt] = wb[(ks * 8 + tt) * 64 + lane];
#pragma unroll
      for (int mt = 0; mt < 2; ++mt)
#pragma unroll
        for (int tt = 0; tt < 8; ++tt)
          acc[mt][tt] = __builtin_amdgcn_mfma_f32_16x16x32_bf16(
              afr[mt], bfr[tt], acc[mt][tt], 0, 0, 0);
    }

#pragma unroll
    for (int mt = 0; mt < 2; ++mt) {
#pragma unroll
      for (int tt = 0; tt < 8; ++tt) {
        f32x4 v = acc[mt][tt];
        float s = fmaxf(v.x + bias[tt], 0.f) + fmaxf(v.y + bias[tt], 0.f)
                + fmaxf(v.z + bias[tt], 0.f) + fmaxf(v.w + bias[tt], 0.f);
        s += __shfl_xor(s, 16);
        s += __shfl_xor(s, 32);
        csum[tt] += s;
      }
    }
  }
  if (lane < 16) {
#pragma unroll
    for (int tt = 0; tt < 8; ++tt) atomicAdd(&lgs[tt * 16 + lane], csum[tt]);
  }
  __syncthreads();
  if (t < 128) atomicAdd(&gsum[t], lgs[t]);
}

// ============ head: out = (gsum/N) @ Wlin.T + blin ============
__global__ void k_final(const float* __restrict__ gsum, const float* __restrict__ Wlin,
                        const float* __restrict__ blin, float* __restrict__ out) {
  int lane = threadIdx.x;  // 64 threads
  float g0 = gsum[lane];
  float g1 = gsum[lane + 64];
  float s0 = g0 * Wlin[lane]       + g1 * Wlin[lane + 64];
  float s1 = g0 * Wlin[128 + lane] + g1 * Wlin[192 + lane];
#pragma unroll
  for (int off = 32; off > 0; off >>= 1) {
    s0 += __shfl_down(s0, off);
    s1 += __shfl_down(s1, off);
  }
  if (lane == 0) {
    const float inv = 1.0f / (float)N_NODES;
    out[0] = s0 * inv + blin[0];
    out[1] = s1 * inv + blin[1];
  }
}

extern "C" void kernel_launch(void* const* d_in, const int* in_sizes, int n_in,
                              void* d_out, int out_size, void* d_ws, size_t ws_size,
                              hipStream_t stream) {
  const float* x       = (const float*)d_in[0];
  const int*   ei      = (const int*)d_in[1];
  const float* W1_rel  = (const float*)d_in[2];
  const float* b1      = (const float*)d_in[3];
  const float* W1_root = (const float*)d_in[4];
  const float* W2_rel  = (const float*)d_in[5];
  const float* b2      = (const float*)d_in[6];
  const float* W2_root = (const float*)d_in[7];
  const float* Wlin    = (const float*)d_in[8];
  const float* blin    = (const float*)d_in[9];
  const int* src = ei;            // edge_index[0]
  const int* dst = ei + N_EDGES;  // edge_index[1]
  float* out = (float*)d_out;

  // workspace layout (bytes):
  //   row_se (int2) @0          : 800,000
  //   bucket_cursor @800,000    : 8,192
  //   gsum          @808,192    : 512
  //   wbuf          @808,832    : 65,536     -> 874,368
  //   csr_src       @874,368    : 9,603,072  -> 10,477,440
  //   ebuf (uint)   @10,477,440 : 9,603,072  -> 20,080,512
  //   h1f8 (fp8)    @20,080,512 : 12,800,000 -> 32,880,512
  //   agg2b (bf16)  @32,880,512 : 25,600,000 -> 58,480,512
  char* ws = (char*)d_ws;
  int2*           row_se        = (int2*)(ws);
  int*            bucket_cursor = (int*)(ws + 800000);
  float*          gsum          = (float*)(ws + 808192);
  unsigned*       wbuf          = (unsigned*)(ws + 808832);
  int*            csr_src       = (int*)(ws + 874368);
  unsigned*       ebuf          = (unsigned*)(ws + 10477440);
  unsigned short* h1f8          = (unsigned short*)(ws + 20080512);
  uint2*          agg2b         = (uint2*)(ws + 32880512);

  k_init <<<1, 512, 0, stream>>>(bucket_cursor, gsum, W2_rel, W2_root, wbuf);
  k_bfill<<<BF_BLOCKS, 512, 0, stream>>>(src, dst, bucket_cursor, ebuf);
  k_fill2<<<NBUCK, 256, 0, stream>>>(ebuf, bucket_cursor, x, W1_rel, b1, W1_root,
                                     row_se, csr_src, h1f8);
  k_pull128<<<(N_NODES / 2 * 64 + 255) / 256, 256, 0, stream>>>(
      (const unsigned*)h1f8, row_se, csr_src, agg2b);
  k_gemm_pool<<<GEMM_BLOCKS, 256, 0, stream>>>(
      (const unsigned*)agg2b, h1f8, wbuf, b2, gsum);
  k_final<<<1, 64, 0, stream>>>(gsum, Wlin, blin, out);
}